// Round 1
// baseline (85.500 us; speedup 1.0000x reference)
//
#include <hip/hip_runtime.h>
#include <math.h>

#define HW   3136   // 56*56
#define NC   512    // channels
#define NB   32     // batch
#define KSEL 256    // top-k

// ---------------------------------------------------------------------------
// Kernel 1: per-(b,c) mean + max over HW spatial elements.
// One wave (64 lanes) per channel row; block of 256 = 4 waves = 4 channels.
// 3136 floats = 784 float4 = 12*64 + 16.
// ---------------------------------------------------------------------------
__global__ __launch_bounds__(256) void reduce_mean_max(
    const float* __restrict__ x, float* __restrict__ avg, float* __restrict__ mx)
{
    const int gwave = (blockIdx.x * blockDim.x + threadIdx.x) >> 6; // = b*NC + c
    const int lane  = threadIdx.x & 63;

    const float4* p = (const float4*)(x + (size_t)gwave * HW);

    float s = 0.0f;
    float m = -INFINITY;
#pragma unroll
    for (int i = 0; i < 12; ++i) {
        float4 v = p[lane + i * 64];
        s += (v.x + v.y) + (v.z + v.w);
        m = fmaxf(m, fmaxf(fmaxf(v.x, v.y), fmaxf(v.z, v.w)));
    }
    if (lane < 16) {
        float4 v = p[lane + 768];
        s += (v.x + v.y) + (v.z + v.w);
        m = fmaxf(m, fmaxf(fmaxf(v.x, v.y), fmaxf(v.z, v.w)));
    }
    // wave-64 tree reduce
#pragma unroll
    for (int off = 32; off > 0; off >>= 1) {
        s += __shfl_down(s, off, 64);
        m = fmaxf(m, __shfl_down(m, off, 64));
    }
    if (lane == 0) {
        avg[gwave] = s * (1.0f / (float)HW);
        mx[gwave]  = m;
    }
}

// ---------------------------------------------------------------------------
// Kernel 2: per-batch conv1d(avg)+conv1d(mx) -> sigmoid -> top-K select.
// One block of 512 threads per batch sample. Rank-based selection with
// lax.top_k tie-break (lower index wins); compaction by ascending channel
// index == the reference's argsort(idx) re-sort.
// ---------------------------------------------------------------------------
__global__ __launch_bounds__(512) void score_topk(
    const float* __restrict__ avg, const float* __restrict__ mx,
    const float* __restrict__ w, int* __restrict__ sidx, float* __restrict__ sval)
{
    const int b = blockIdx.x;
    const int c = threadIdx.x;

    __shared__ float s_d[NC + 2];   // avg+max descriptor, zero-padded halo
    __shared__ float s_score[NC];
    __shared__ int   s_flag[NC];

    if (c == 0) { s_d[0] = 0.0f; s_d[NC + 1] = 0.0f; }
    s_d[c + 1] = avg[b * NC + c] + mx[b * NC + c];
    __syncthreads();

    const float w0 = w[0], w1 = w[1], w2 = w[2];
    // cross-correlation (lax conv does NOT flip the kernel)
    const float t = s_d[c] * w0 + s_d[c + 1] * w1 + s_d[c + 2] * w2;
    const float score = 1.0f / (1.0f + expf(-t));
    s_score[c] = score;
    __syncthreads();

    int rank = 0;
    for (int j = 0; j < NC; ++j) {
        const float sj = s_score[j];
        rank += (sj > score) || (sj == score && j < c);
    }
    const int flag = (rank < KSEL) ? 1 : 0;
    s_flag[c] = flag;
    __syncthreads();

    if (flag) {
        int pos = 0;
        for (int j = 0; j < c; ++j) pos += s_flag[j];
        sidx[b * KSEL + pos] = c;
        sval[b * KSEL + pos] = score;
    }
}

// ---------------------------------------------------------------------------
// Kernel 3: gather selected channels and scale. One block per (b,k).
// ---------------------------------------------------------------------------
__global__ __launch_bounds__(256) void gather_scale(
    const float* __restrict__ x, const int* __restrict__ sidx,
    const float* __restrict__ sval, float* __restrict__ out)
{
    const int bk = blockIdx.x;          // b*KSEL + k
    const int b  = bk >> 8;             // KSEL == 256
    const int ch = sidx[bk];
    const float sv = sval[bk];

    const float4* src = (const float4*)(x + ((size_t)b * NC + ch) * HW);
    float4*       dst = (float4*)(out + (size_t)bk * HW);

    const int t = threadIdx.x;
#pragma unroll
    for (int i = 0; i < 3; ++i) {
        float4 v = src[t + i * 256];
        v.x *= sv; v.y *= sv; v.z *= sv; v.w *= sv;
        dst[t + i * 256] = v;
    }
    if (t < 16) {
        float4 v = src[t + 768];
        v.x *= sv; v.y *= sv; v.z *= sv; v.w *= sv;
        dst[t + 768] = v;
    }
}

extern "C" void kernel_launch(void* const* d_in, const int* in_sizes, int n_in,
                              void* d_out, int out_size, void* d_ws, size_t ws_size,
                              hipStream_t stream)
{
    const float* x = (const float*)d_in[0];   // [32,512,56,56]
    const float* w = (const float*)d_in[1];   // [1,1,3] -> 3 floats
    float* out = (float*)d_out;               // [32,256,56,56]

    // workspace layout (floats): avg[16384] | mx[16384] | sval[8192] | sidx[8192 ints]
    float* avg  = (float*)d_ws;
    float* mx   = avg + NB * NC;
    float* sval = mx + NB * NC;
    int*   sidx = (int*)(sval + NB * KSEL);

    // Kernel 1: 16384 channel rows, 1 wave each, 4 waves/block -> 4096 blocks
    reduce_mean_max<<<(NB * NC) / 4, 256, 0, stream>>>(x, avg, mx);

    // Kernel 2: one block per batch sample
    score_topk<<<NB, NC, 0, stream>>>(avg, mx, w, sidx, sval);

    // Kernel 3: one block per selected (b,k) channel
    gather_scale<<<NB * KSEL, 256, 0, stream>>>(x, sidx, sval, out);
}

// Round 2
// 80.728 us; speedup vs baseline: 1.0591x; 1.0591x over previous
//
#include <hip/hip_runtime.h>
#include <math.h>

#define HW   3136   // 56*56
#define NC   512    // channels
#define NB   32     // batch
#define KSEL 256    // top-k

typedef float f32x4 __attribute__((ext_vector_type(4)));

// ---------------------------------------------------------------------------
// Kernel 1: per-(b,c) mean + max over HW spatial elements.
// One wave (64 lanes) per channel row; block of 256 = 4 waves = 4 channels.
// 3136 floats = 784 float4 = 12*64 + 16. Regular loads -> x allocates in L3
// (205.5 MB < 256 MB Infinity Cache) so kernel 3 re-reads hit L3.
// ---------------------------------------------------------------------------
__global__ __launch_bounds__(256) void reduce_mean_max(
    const float* __restrict__ x, float* __restrict__ avg, float* __restrict__ mx)
{
    const int gwave = (blockIdx.x * blockDim.x + threadIdx.x) >> 6; // = b*NC + c
    const int lane  = threadIdx.x & 63;

    const f32x4* p = (const f32x4*)(x + (size_t)gwave * HW);

    float s = 0.0f;
    float m = -INFINITY;
#pragma unroll
    for (int i = 0; i < 12; ++i) {
        f32x4 v = p[lane + i * 64];
        s += (v.x + v.y) + (v.z + v.w);
        m = fmaxf(m, fmaxf(fmaxf(v.x, v.y), fmaxf(v.z, v.w)));
    }
    if (lane < 16) {
        f32x4 v = p[lane + 768];
        s += (v.x + v.y) + (v.z + v.w);
        m = fmaxf(m, fmaxf(fmaxf(v.x, v.y), fmaxf(v.z, v.w)));
    }
    // wave-64 tree reduce
#pragma unroll
    for (int off = 32; off > 0; off >>= 1) {
        s += __shfl_down(s, off, 64);
        m = fmaxf(m, __shfl_down(m, off, 64));
    }
    if (lane == 0) {
        avg[gwave] = s * (1.0f / (float)HW);
        mx[gwave]  = m;
    }
}

// ---------------------------------------------------------------------------
// Kernel 2: per-batch conv1d(avg+mx) -> sigmoid -> top-K select.
// One block of 512 threads per batch sample. Rank-based selection with
// lax.top_k tie-break (lower index wins); ballot-based compaction emits
// selected channels in ascending index order == reference's argsort re-sort.
// ---------------------------------------------------------------------------
__global__ __launch_bounds__(512) void score_topk(
    const float* __restrict__ avg, const float* __restrict__ mx,
    const float* __restrict__ w, int* __restrict__ sidx, float* __restrict__ sval)
{
    const int b = blockIdx.x;
    const int c = threadIdx.x;

    __shared__ float s_d[NC + 2];   // avg+max descriptor, zero-padded halo
    __shared__ float s_score[NC];
    __shared__ int   s_wcnt[8];     // per-wave selected count

    if (c == 0) { s_d[0] = 0.0f; s_d[NC + 1] = 0.0f; }
    s_d[c + 1] = avg[b * NC + c] + mx[b * NC + c];
    __syncthreads();

    const float w0 = w[0], w1 = w[1], w2 = w[2];
    // cross-correlation (lax conv does NOT flip the kernel)
    const float t = s_d[c] * w0 + s_d[c + 1] * w1 + s_d[c + 2] * w2;
    const float score = 1.0f / (1.0f + expf(-t));
    s_score[c] = score;
    __syncthreads();

    int rank = 0;
    for (int j = 0; j < NC; ++j) {
        const float sj = s_score[j];
        rank += (sj > score) || (sj == score && j < c);
    }
    const int flag = (rank < KSEL) ? 1 : 0;

    const unsigned long long bal = __ballot(flag);
    const int wid  = c >> 6;
    const int lane = c & 63;
    if (lane == 0) s_wcnt[wid] = __popcll(bal);
    __syncthreads();

    if (flag) {
        int pos = __popcll(bal & ((1ULL << lane) - 1ULL));
        for (int wj = 0; wj < wid; ++wj) pos += s_wcnt[wj];
        sidx[b * KSEL + pos] = c;
        sval[b * KSEL + pos] = score;
    }
}

// ---------------------------------------------------------------------------
// Kernel 3: gather selected channels and scale. One block per (b,k).
// Reads of x should hit L3 (fetched by kernel 1); output stores are
// NON-TEMPORAL so they don't evict x from Infinity Cache.
// ---------------------------------------------------------------------------
__global__ __launch_bounds__(256) void gather_scale(
    const float* __restrict__ x, const int* __restrict__ sidx,
    const float* __restrict__ sval, float* __restrict__ out)
{
    const int bk = blockIdx.x;          // b*KSEL + k
    const int b  = bk >> 8;             // KSEL == 256
    const int ch = sidx[bk];
    const float sv = sval[bk];

    const f32x4* src = (const f32x4*)(x + ((size_t)b * NC + ch) * HW);
    f32x4*       dst = (f32x4*)(out + (size_t)bk * HW);

    const int t = threadIdx.x;
#pragma unroll
    for (int i = 0; i < 3; ++i) {
        f32x4 v = src[t + i * 256];
        v.x *= sv; v.y *= sv; v.z *= sv; v.w *= sv;
        __builtin_nontemporal_store(v, &dst[t + i * 256]);
    }
    if (t < 16) {
        f32x4 v = src[t + 768];
        v.x *= sv; v.y *= sv; v.z *= sv; v.w *= sv;
        __builtin_nontemporal_store(v, &dst[t + 768]);
    }
}

extern "C" void kernel_launch(void* const* d_in, const int* in_sizes, int n_in,
                              void* d_out, int out_size, void* d_ws, size_t ws_size,
                              hipStream_t stream)
{
    const float* x = (const float*)d_in[0];   // [32,512,56,56]
    const float* w = (const float*)d_in[1];   // [1,1,3] -> 3 floats
    float* out = (float*)d_out;               // [32,256,56,56]

    // workspace layout (floats): avg[16384] | mx[16384] | sval[8192] | sidx[8192 ints]
    float* avg  = (float*)d_ws;
    float* mx   = avg + NB * NC;
    float* sval = mx + NB * NC;
    int*   sidx = (int*)(sval + NB * KSEL);

    // Kernel 1: 16384 channel rows, 1 wave each, 4 waves/block -> 4096 blocks
    reduce_mean_max<<<(NB * NC) / 4, 256, 0, stream>>>(x, avg, mx);

    // Kernel 2: one block per batch sample
    score_topk<<<NB, NC, 0, stream>>>(avg, mx, w, sidx, sval);

    // Kernel 3: one block per selected (b,k) channel
    gather_scale<<<NB * KSEL, 256, 0, stream>>>(x, sidx, sval, out);
}